// Round 3
// baseline (492.747 us; speedup 1.0000x reference)
//
#include <hip/hip_runtime.h>
#include <math.h>

#define N_NODES 50000
#define DIM     128
#define NHEAD   4
#define NCH     16
#define HC      64
#define NE      800000
#define EDIM    64
#define NEG     0.2f

__device__ __forceinline__ float lrelu(float v) { return v > 0.f ? v : NEG * v; }

// ---------------- K1: v_edge[h][d] = sum_c att_edge[h,c] * W_edge[h*16+c, d] ----------------
__global__ void k1_vedge(const float* __restrict__ W_edge, const float* __restrict__ att_edge,
                         float* __restrict__ v_edge) {
    int t = threadIdx.x;          // 256 threads
    int h = t >> 6, d = t & 63;
    float acc = 0.f;
    #pragma unroll
    for (int c = 0; c < NCH; ++c)
        acc = fmaf(att_edge[h * NCH + c], W_edge[(h * NCH + c) * EDIM + d], acc);
    v_edge[h * 64 + d] = acc;
}

// ---------------- K2: xh = x @ W^T  [N,64]; a_src/a_dst [N,4] ----------------
__global__ __launch_bounds__(256) void k2_xh(const float* __restrict__ x, const float* __restrict__ W,
                                             const float* __restrict__ att_src, const float* __restrict__ att_dst,
                                             float* __restrict__ xh, float* __restrict__ a_src,
                                             float* __restrict__ a_dst) {
    __shared__ float Wt[128 * 68];   // Wt[k*68 + col]
    int t = threadIdx.x;
    for (int idx = t; idx < 64 * 128; idx += 256) {
        int col = idx >> 7, k = idx & 127;
        Wt[k * 68 + col] = W[idx];
    }
    __syncthreads();

    int h  = t & 3;
    int rp = t >> 2;                       // 0..63
    int row0 = blockIdx.x * 128 + rp * 2;  // this thread: rows row0, row0+1, head h
    int r0 = min(row0, N_NODES - 1);
    int r1 = min(row0 + 1, N_NODES - 1);
    const float4* x0 = (const float4*)(x + (size_t)r0 * DIM);
    const float4* x1 = (const float4*)(x + (size_t)r1 * DIM);

    float acc0[16], acc1[16];
    #pragma unroll
    for (int c = 0; c < 16; ++c) { acc0[c] = 0.f; acc1[c] = 0.f; }

    for (int k4 = 0; k4 < 32; ++k4) {
        float4 xa = x0[k4];
        float4 xb = x1[k4];
        #pragma unroll
        for (int kk = 0; kk < 4; ++kk) {
            float va = (&xa.x)[kk];
            float vb = (&xb.x)[kk];
            const float* wr = &Wt[(k4 * 4 + kk) * 68 + h * 16];
            #pragma unroll
            for (int j = 0; j < 4; ++j) {
                float4 w = *(const float4*)(wr + 4 * j);
                acc0[4 * j + 0] = fmaf(va, w.x, acc0[4 * j + 0]);
                acc0[4 * j + 1] = fmaf(va, w.y, acc0[4 * j + 1]);
                acc0[4 * j + 2] = fmaf(va, w.z, acc0[4 * j + 2]);
                acc0[4 * j + 3] = fmaf(va, w.w, acc0[4 * j + 3]);
                acc1[4 * j + 0] = fmaf(vb, w.x, acc1[4 * j + 0]);
                acc1[4 * j + 1] = fmaf(vb, w.y, acc1[4 * j + 1]);
                acc1[4 * j + 2] = fmaf(vb, w.z, acc1[4 * j + 2]);
                acc1[4 * j + 3] = fmaf(vb, w.w, acc1[4 * j + 3]);
            }
        }
    }

    if (row0 < N_NODES) {
        float4* o = (float4*)(xh + (size_t)row0 * HC + h * 16);
        o[0] = make_float4(acc0[0], acc0[1], acc0[2], acc0[3]);
        o[1] = make_float4(acc0[4], acc0[5], acc0[6], acc0[7]);
        o[2] = make_float4(acc0[8], acc0[9], acc0[10], acc0[11]);
        o[3] = make_float4(acc0[12], acc0[13], acc0[14], acc0[15]);
        float ss = 0.f, sd = 0.f;
        #pragma unroll
        for (int c = 0; c < 16; ++c) {
            ss = fmaf(acc0[c], att_src[h * 16 + c], ss);
            sd = fmaf(acc0[c], att_dst[h * 16 + c], sd);
        }
        a_src[row0 * 4 + h] = ss;
        a_dst[row0 * 4 + h] = sd;
    }
    if (row0 + 1 < N_NODES) {
        float4* o = (float4*)(xh + (size_t)(row0 + 1) * HC + h * 16);
        o[0] = make_float4(acc1[0], acc1[1], acc1[2], acc1[3]);
        o[1] = make_float4(acc1[4], acc1[5], acc1[6], acc1[7]);
        o[2] = make_float4(acc1[8], acc1[9], acc1[10], acc1[11]);
        o[3] = make_float4(acc1[12], acc1[13], acc1[14], acc1[15]);
        float ss = 0.f, sd = 0.f;
        #pragma unroll
        for (int c = 0; c < 16; ++c) {
            ss = fmaf(acc1[c], att_src[h * 16 + c], ss);
            sd = fmaf(acc1[c], att_dst[h * 16 + c], sd);
        }
        a_src[(row0 + 1) * 4 + h] = ss;
        a_dst[(row0 + 1) * 4 + h] = sd;
    }
}

// ---------------- KP: wave-cooperative edge pass ----------------
// 16 lanes per edge, 4 edges per wave iteration: one fully-coalesced 1KB load.
// Writes p_e[E,4] in EDGE order (coalesced) and fuses the deg histogram.
__global__ __launch_bounds__(256) void kp_edge(const float* __restrict__ edge_attr,
                                               const int* __restrict__ ei,
                                               const float* __restrict__ v_edge,
                                               float* __restrict__ p_e,
                                               int* __restrict__ deg) {
    int lane = threadIdx.x & 63;
    int q = lane & 15;          // feature quarter 0..15 (features q*4..q*4+3)
    // per-lane fragment of v_edge for all 4 heads
    float4 w0 = *(const float4*)(v_edge + 0 * 64 + q * 4);
    float4 w1 = *(const float4*)(v_edge + 1 * 64 + q * 4);
    float4 w2 = *(const float4*)(v_edge + 2 * 64 + q * 4);
    float4 w3 = *(const float4*)(v_edge + 3 * 64 + q * 4);

    int wave   = (blockIdx.x * 256 + threadIdx.x) >> 6;
    int nwaves = gridDim.x * 4;
    // each group g covers edges 4g..4g+3 ; NE % 4 == 0 so no tail
    for (int g = wave; g < NE / 4; g += nwaves) {
        // coalesced: lane l loads float4 at edge_attr + g*256 + l*4
        float4 v = *(const float4*)(edge_attr + (size_t)g * 256 + lane * 4);
        float p0 = fmaf(v.x, w0.x, fmaf(v.y, w0.y, fmaf(v.z, w0.z, v.w * w0.w)));
        float p1 = fmaf(v.x, w1.x, fmaf(v.y, w1.y, fmaf(v.z, w1.z, v.w * w1.w)));
        float p2 = fmaf(v.x, w2.x, fmaf(v.y, w2.y, fmaf(v.z, w2.z, v.w * w2.w)));
        float p3 = fmaf(v.x, w3.x, fmaf(v.y, w3.y, fmaf(v.z, w3.z, v.w * w3.w)));
        // reduce over the 16-lane group (lane bits 0..3)
        #pragma unroll
        for (int m = 1; m < 16; m <<= 1) {
            p0 += __shfl_xor(p0, m);
            p1 += __shfl_xor(p1, m);
            p2 += __shfl_xor(p2, m);
            p3 += __shfl_xor(p3, m);
        }
        int e = g * 4 + (lane >> 4);
        if (q < 4) {
            float pv = (q == 0) ? p0 : (q == 1) ? p1 : (q == 2) ? p2 : p3;
            p_e[(size_t)e * 4 + q] = pv;        // 16 lanes -> one 64B line
        }
        if (q == 0)
            atomicAdd(deg + ei[NE + e], 1);     // fire-and-forget
    }
}

// ---------------- K4: 3-kernel exclusive scan of deg -> rowptr, cursor ----------------
__global__ void k4a_scan(const int* __restrict__ deg, int* __restrict__ tmp, int* __restrict__ bsums) {
    int t = threadIdx.x;
    int i = blockIdx.x * 256 + t;
    int v = (i < N_NODES) ? deg[i] : 0;
    int lane = t & 63, w = t >> 6;
    int xv = v;
    #pragma unroll
    for (int o = 1; o < 64; o <<= 1) {
        int y = __shfl_up(xv, o);
        if (lane >= o) xv += y;
    }
    __shared__ int wtot[4];
    if (lane == 63) wtot[w] = xv;
    __syncthreads();
    int add = 0;
    #pragma unroll
    for (int j = 0; j < 4; ++j)
        if (j < w) add += wtot[j];
    xv += add;
    if (i < N_NODES) tmp[i] = xv;            // inclusive within block
    if (t == 255) bsums[blockIdx.x] = xv;    // block total
}

__global__ void k4b_scan(int* __restrict__ bsums, int nb) {
    int t = threadIdx.x;
    int v = (t < nb) ? bsums[t] : 0;
    int lane = t & 63, w = t >> 6;
    int xv = v;
    #pragma unroll
    for (int o = 1; o < 64; o <<= 1) {
        int y = __shfl_up(xv, o);
        if (lane >= o) xv += y;
    }
    __shared__ int wtot[4];
    if (lane == 63) wtot[w] = xv;
    __syncthreads();
    int add = 0;
    #pragma unroll
    for (int j = 0; j < 4; ++j)
        if (j < w) add += wtot[j];
    xv += add;
    if (t < nb) bsums[t] = xv - v;           // exclusive block offset
}

__global__ void k4c_finish(const int* __restrict__ tmp, const int* __restrict__ bsums,
                           const int* __restrict__ deg, int* __restrict__ rowptr,
                           int* __restrict__ cursor) {
    int i = blockIdx.x * 256 + threadIdx.x;
    if (i >= N_NODES) return;
    int incl = tmp[i] + bsums[i >> 8];
    rowptr[i + 1] = incl;
    cursor[i] = incl - deg[i];
    if (i == 0) rowptr[0] = 0;
}

// ---------------- K5: permutation scatter (only 4B/edge scattered) ----------------
__global__ __launch_bounds__(256) void k5_perm(const int* __restrict__ ei,
                                               int* __restrict__ cursor,
                                               int* __restrict__ perm) {
    int e = blockIdx.x * 256 + threadIdx.x;
    if (e >= NE) return;
    int dst = ei[NE + e];
    int pos = atomicAdd(cursor + dst, 1);
    perm[pos] = e;
}

// ---------------- K6: wave per node — self-loop mean + softmax denom + aggregation ----------------
__global__ __launch_bounds__(256) void k6_agg(const int* __restrict__ rowptr,
                                              const int* __restrict__ perm,
                                              const int* __restrict__ ei,
                                              const float* __restrict__ p_e,
                                              const float* __restrict__ xh,
                                              const float* __restrict__ a_src,
                                              const float* __restrict__ a_dst,
                                              const float* __restrict__ bias,
                                              float* __restrict__ out) {
    int lane = threadIdx.x & 63;
    int n = blockIdx.x * 4 + (threadIdx.x >> 6);
    if (n >= N_NODES) return;
    int start = rowptr[n], end = rowptr[n + 1];
    int degn = end - start;

    // phase 1: per-head exp-weight sum + raw-p sum.  lane = slot*4 + h
    int h = lane & 3;
    float adh = a_dst[n * 4 + h];
    float sw = 0.f, sp = 0.f;
    for (int i = start + (lane >> 2); i < end; i += 16) {
        int e  = perm[i];
        int s  = ei[e];
        float p = p_e[(size_t)e * 4 + h];
        float a = a_src[(size_t)s * 4 + h];
        sw += __expf(lrelu(a + adh + p));
        sp += p;
    }
    sw += __shfl_xor(sw, 4);  sp += __shfl_xor(sp, 4);
    sw += __shfl_xor(sw, 8);  sp += __shfl_xor(sp, 8);
    sw += __shfl_xor(sw, 16); sp += __shfl_xor(sp, 16);
    sw += __shfl_xor(sw, 32); sp += __shfl_xor(sp, 32);

    float al    = sp / fmaxf((float)degn, 1.f);
    float wself = __expf(lrelu(a_src[n * 4 + h] + adh + al));
    float denom = sw + wself + 1e-16f;

    // phase 2: accumulate. lane = h2*16 + c
    int h2 = lane >> 4;
    float d2   = __shfl(denom, h2);
    float ws2  = __shfl(wself, h2);
    float adh2 = __shfl(adh, h2);
    float acc = ws2 * xh[(size_t)n * HC + lane];

    int i = start;
    for (; i + 4 <= end; i += 4) {
        int e0 = perm[i], e1 = perm[i + 1], e2 = perm[i + 2], e3 = perm[i + 3];
        int s0 = ei[e0], s1 = ei[e1], s2 = ei[e2], s3 = ei[e3];
        float p0 = p_e[(size_t)e0 * 4 + h2];
        float p1 = p_e[(size_t)e1 * 4 + h2];
        float p2 = p_e[(size_t)e2 * 4 + h2];
        float p3 = p_e[(size_t)e3 * 4 + h2];
        float w0 = __expf(lrelu(a_src[(size_t)s0 * 4 + h2] + adh2 + p0));
        float w1 = __expf(lrelu(a_src[(size_t)s1 * 4 + h2] + adh2 + p1));
        float w2 = __expf(lrelu(a_src[(size_t)s2 * 4 + h2] + adh2 + p2));
        float w3 = __expf(lrelu(a_src[(size_t)s3 * 4 + h2] + adh2 + p3));
        float x0 = xh[(size_t)s0 * HC + lane];
        float x1 = xh[(size_t)s1 * HC + lane];
        float x2 = xh[(size_t)s2 * HC + lane];
        float x3 = xh[(size_t)s3 * HC + lane];
        acc = fmaf(w0, x0, acc);
        acc = fmaf(w1, x1, acc);
        acc = fmaf(w2, x2, acc);
        acc = fmaf(w3, x3, acc);
    }
    for (; i < end; ++i) {
        int ev = perm[i];
        int sv = ei[ev];
        float pv = p_e[(size_t)ev * 4 + h2];
        float wv = __expf(lrelu(a_src[(size_t)sv * 4 + h2] + adh2 + pv));
        acc = fmaf(wv, xh[(size_t)sv * HC + lane], acc);
    }
    out[(size_t)n * HC + lane] = acc / d2 + bias[lane];
}

// ---------------- launcher ----------------
extern "C" void kernel_launch(void* const* d_in, const int* in_sizes, int n_in,
                              void* d_out, int out_size, void* d_ws, size_t ws_size,
                              hipStream_t stream) {
    const float* x         = (const float*)d_in[0];
    const int*   ei        = (const int*)d_in[1];
    const float* edge_attr = (const float*)d_in[2];
    const float* W         = (const float*)d_in[3];
    const float* W_edge    = (const float*)d_in[4];
    const float* att_src   = (const float*)d_in[5];
    const float* att_dst   = (const float*)d_in[6];
    const float* att_edge  = (const float*)d_in[7];
    const float* bias      = (const float*)d_in[8];
    float* out = (float*)d_out;

    char* ws = (char*)d_ws;
    size_t off = 0;
    float* v_edge    = (float*)(ws + off); off += 1024;                      // 256 f
    float* xh        = (float*)(ws + off); off += (size_t)N_NODES * HC * 4;  // 12.8 MB
    float* a_src     = (float*)(ws + off); off += (size_t)N_NODES * 4 * 4;
    float* a_dst     = (float*)(ws + off); off += (size_t)N_NODES * 4 * 4;
    int*   deg       = (int*)(ws + off);   off += (size_t)N_NODES * 4;
    int*   tmp       = (int*)(ws + off);   off += (size_t)N_NODES * 4;
    int*   bsums     = (int*)(ws + off);   off += 1024;
    int*   rowptr    = (int*)(ws + off);   off += (size_t)(N_NODES + 4) * 4;
    int*   cursor    = (int*)(ws + off);   off += (size_t)N_NODES * 4;
    int*   perm      = (int*)(ws + off);   off += (size_t)NE * 4;            // 3.2 MB
    float* p_e       = (float*)(ws + off); off += (size_t)NE * 4 * 4;        // 12.8 MB

    hipMemsetAsync(deg, 0, (size_t)N_NODES * 4, stream);

    k1_vedge<<<1, 256, 0, stream>>>(W_edge, att_edge, v_edge);
    k2_xh<<<(N_NODES + 127) / 128, 256, 0, stream>>>(x, W, att_src, att_dst, xh, a_src, a_dst);
    kp_edge<<<1024, 256, 0, stream>>>(edge_attr, ei, v_edge, p_e, deg);
    int nb = (N_NODES + 255) / 256;   // 196
    k4a_scan<<<nb, 256, 0, stream>>>(deg, tmp, bsums);
    k4b_scan<<<1, 256, 0, stream>>>(bsums, nb);
    k4c_finish<<<nb, 256, 0, stream>>>(tmp, bsums, deg, rowptr, cursor);
    k5_perm<<<(NE + 255) / 256, 256, 0, stream>>>(ei, cursor, perm);
    k6_agg<<<(N_NODES + 3) / 4, 256, 0, stream>>>(rowptr, perm, ei, p_e, xh,
                                                  a_src, a_dst, bias, out);
}

// Round 4
// 472.232 us; speedup vs baseline: 1.0434x; 1.0434x over previous
//
#include <hip/hip_runtime.h>
#include <math.h>

#define N_NODES 50000
#define DIM     128
#define NHEAD   4
#define NCH     16
#define HC      64
#define NE      800000
#define EDIM    64
#define NEG     0.2f
#define MAXE    64

__device__ __forceinline__ float lrelu(float v) { return v > 0.f ? v : NEG * v; }

// ---------------- K1: v_edge[h][d] = sum_c att_edge[h,c] * W_edge[h*16+c, d] ----------------
__global__ void k1_vedge(const float* __restrict__ W_edge, const float* __restrict__ att_edge,
                         float* __restrict__ v_edge) {
    int t = threadIdx.x;          // 256 threads
    int h = t >> 6, d = t & 63;
    float acc = 0.f;
    #pragma unroll
    for (int c = 0; c < NCH; ++c)
        acc = fmaf(att_edge[h * NCH + c], W_edge[(h * NCH + c) * EDIM + d], acc);
    v_edge[h * 64 + d] = acc;
}

// ---------------- K2: xh = x @ W^T  [N,64]; a_src/a_dst [N,4] ----------------
__global__ __launch_bounds__(256) void k2_xh(const float* __restrict__ x, const float* __restrict__ W,
                                             const float* __restrict__ att_src, const float* __restrict__ att_dst,
                                             float* __restrict__ xh, float* __restrict__ a_src,
                                             float* __restrict__ a_dst) {
    __shared__ float Wt[128 * 68];   // Wt[k*68 + col]
    int t = threadIdx.x;
    for (int idx = t; idx < 64 * 128; idx += 256) {
        int col = idx >> 7, k = idx & 127;
        Wt[k * 68 + col] = W[idx];
    }
    __syncthreads();

    int h  = t & 3;
    int rp = t >> 2;                       // 0..63
    int row0 = blockIdx.x * 128 + rp * 2;  // this thread: rows row0, row0+1, head h
    int r0 = min(row0, N_NODES - 1);
    int r1 = min(row0 + 1, N_NODES - 1);
    const float4* x0 = (const float4*)(x + (size_t)r0 * DIM);
    const float4* x1 = (const float4*)(x + (size_t)r1 * DIM);

    float acc0[16], acc1[16];
    #pragma unroll
    for (int c = 0; c < 16; ++c) { acc0[c] = 0.f; acc1[c] = 0.f; }

    for (int k4 = 0; k4 < 32; ++k4) {
        float4 xa = x0[k4];
        float4 xb = x1[k4];
        #pragma unroll
        for (int kk = 0; kk < 4; ++kk) {
            float va = (&xa.x)[kk];
            float vb = (&xb.x)[kk];
            const float* wr = &Wt[(k4 * 4 + kk) * 68 + h * 16];
            #pragma unroll
            for (int j = 0; j < 4; ++j) {
                float4 w = *(const float4*)(wr + 4 * j);
                acc0[4 * j + 0] = fmaf(va, w.x, acc0[4 * j + 0]);
                acc0[4 * j + 1] = fmaf(va, w.y, acc0[4 * j + 1]);
                acc0[4 * j + 2] = fmaf(va, w.z, acc0[4 * j + 2]);
                acc0[4 * j + 3] = fmaf(va, w.w, acc0[4 * j + 3]);
                acc1[4 * j + 0] = fmaf(vb, w.x, acc1[4 * j + 0]);
                acc1[4 * j + 1] = fmaf(vb, w.y, acc1[4 * j + 1]);
                acc1[4 * j + 2] = fmaf(vb, w.z, acc1[4 * j + 2]);
                acc1[4 * j + 3] = fmaf(vb, w.w, acc1[4 * j + 3]);
            }
        }
    }

    if (row0 < N_NODES) {
        float4* o = (float4*)(xh + (size_t)row0 * HC + h * 16);
        o[0] = make_float4(acc0[0], acc0[1], acc0[2], acc0[3]);
        o[1] = make_float4(acc0[4], acc0[5], acc0[6], acc0[7]);
        o[2] = make_float4(acc0[8], acc0[9], acc0[10], acc0[11]);
        o[3] = make_float4(acc0[12], acc0[13], acc0[14], acc0[15]);
        float ss = 0.f, sd = 0.f;
        #pragma unroll
        for (int c = 0; c < 16; ++c) {
            ss = fmaf(acc0[c], att_src[h * 16 + c], ss);
            sd = fmaf(acc0[c], att_dst[h * 16 + c], sd);
        }
        a_src[row0 * 4 + h] = ss;
        a_dst[row0 * 4 + h] = sd;
    }
    if (row0 + 1 < N_NODES) {
        float4* o = (float4*)(xh + (size_t)(row0 + 1) * HC + h * 16);
        o[0] = make_float4(acc1[0], acc1[1], acc1[2], acc1[3]);
        o[1] = make_float4(acc1[4], acc1[5], acc1[6], acc1[7]);
        o[2] = make_float4(acc1[8], acc1[9], acc1[10], acc1[11]);
        o[3] = make_float4(acc1[12], acc1[13], acc1[14], acc1[15]);
        float ss = 0.f, sd = 0.f;
        #pragma unroll
        for (int c = 0; c < 16; ++c) {
            ss = fmaf(acc1[c], att_src[h * 16 + c], ss);
            sd = fmaf(acc1[c], att_dst[h * 16 + c], sd);
        }
        a_src[(row0 + 1) * 4 + h] = ss;
        a_dst[(row0 + 1) * 4 + h] = sd;
    }
}

// ---------------- KP: wave-cooperative edge pass ----------------
// 16 lanes per edge, 4 edges per wave iteration: one fully-coalesced 1KB load.
// Writes p_e[E,4] in EDGE order (coalesced) and fuses the deg histogram.
__global__ __launch_bounds__(256) void kp_edge(const float* __restrict__ edge_attr,
                                               const int* __restrict__ ei,
                                               const float* __restrict__ v_edge,
                                               float* __restrict__ p_e,
                                               int* __restrict__ deg) {
    int lane = threadIdx.x & 63;
    int q = lane & 15;          // feature quarter 0..15 (features q*4..q*4+3)
    float4 w0 = *(const float4*)(v_edge + 0 * 64 + q * 4);
    float4 w1 = *(const float4*)(v_edge + 1 * 64 + q * 4);
    float4 w2 = *(const float4*)(v_edge + 2 * 64 + q * 4);
    float4 w3 = *(const float4*)(v_edge + 3 * 64 + q * 4);

    int wave   = (blockIdx.x * 256 + threadIdx.x) >> 6;
    int nwaves = gridDim.x * 4;
    for (int g = wave; g < NE / 4; g += nwaves) {
        float4 v = *(const float4*)(edge_attr + (size_t)g * 256 + lane * 4);
        float p0 = fmaf(v.x, w0.x, fmaf(v.y, w0.y, fmaf(v.z, w0.z, v.w * w0.w)));
        float p1 = fmaf(v.x, w1.x, fmaf(v.y, w1.y, fmaf(v.z, w1.z, v.w * w1.w)));
        float p2 = fmaf(v.x, w2.x, fmaf(v.y, w2.y, fmaf(v.z, w2.z, v.w * w2.w)));
        float p3 = fmaf(v.x, w3.x, fmaf(v.y, w3.y, fmaf(v.z, w3.z, v.w * w3.w)));
        #pragma unroll
        for (int m = 1; m < 16; m <<= 1) {
            p0 += __shfl_xor(p0, m);
            p1 += __shfl_xor(p1, m);
            p2 += __shfl_xor(p2, m);
            p3 += __shfl_xor(p3, m);
        }
        int e = g * 4 + (lane >> 4);
        if (q < 4) {
            float pv = (q == 0) ? p0 : (q == 1) ? p1 : (q == 2) ? p2 : p3;
            p_e[(size_t)e * 4 + q] = pv;        // 16 lanes -> one 64B line
        }
        if (q == 0)
            atomicAdd(deg + ei[NE + e], 1);     // fire-and-forget
    }
}

// ---------------- K4: 3-kernel exclusive scan of deg -> rowptr, cursor ----------------
__global__ void k4a_scan(const int* __restrict__ deg, int* __restrict__ tmp, int* __restrict__ bsums) {
    int t = threadIdx.x;
    int i = blockIdx.x * 256 + t;
    int v = (i < N_NODES) ? deg[i] : 0;
    int lane = t & 63, w = t >> 6;
    int xv = v;
    #pragma unroll
    for (int o = 1; o < 64; o <<= 1) {
        int y = __shfl_up(xv, o);
        if (lane >= o) xv += y;
    }
    __shared__ int wtot[4];
    if (lane == 63) wtot[w] = xv;
    __syncthreads();
    int add = 0;
    #pragma unroll
    for (int j = 0; j < 4; ++j)
        if (j < w) add += wtot[j];
    xv += add;
    if (i < N_NODES) tmp[i] = xv;            // inclusive within block
    if (t == 255) bsums[blockIdx.x] = xv;    // block total
}

__global__ void k4b_scan(int* __restrict__ bsums, int nb) {
    int t = threadIdx.x;
    int v = (t < nb) ? bsums[t] : 0;
    int lane = t & 63, w = t >> 6;
    int xv = v;
    #pragma unroll
    for (int o = 1; o < 64; o <<= 1) {
        int y = __shfl_up(xv, o);
        if (lane >= o) xv += y;
    }
    __shared__ int wtot[4];
    if (lane == 63) wtot[w] = xv;
    __syncthreads();
    int add = 0;
    #pragma unroll
    for (int j = 0; j < 4; ++j)
        if (j < w) add += wtot[j];
    xv += add;
    if (t < nb) bsums[t] = xv - v;           // exclusive block offset
}

__global__ void k4c_finish(const int* __restrict__ tmp, const int* __restrict__ bsums,
                           const int* __restrict__ deg, int* __restrict__ rowptr,
                           int* __restrict__ cursor) {
    int i = blockIdx.x * 256 + threadIdx.x;
    if (i >= N_NODES) return;
    int incl = tmp[i] + bsums[i >> 8];
    rowptr[i + 1] = incl;
    cursor[i] = incl - deg[i];
    if (i == 0) rowptr[0] = 0;
}

// ---------------- K5: permutation scatter (only 4B/edge scattered) ----------------
__global__ __launch_bounds__(256) void k5_perm(const int* __restrict__ ei,
                                               int* __restrict__ cursor,
                                               int* __restrict__ perm) {
    int e = blockIdx.x * 256 + threadIdx.x;
    if (e >= NE) return;
    int dst = ei[NE + e];
    int pos = atomicAdd(cursor + dst, 1);
    perm[pos] = e;
}

// ---------------- K6: wave per node, LDS-staged edges ----------------
// phase0: gather this node's edges (src id + p[4]) into LDS once.
// phase1: compute w=exp(lrelu(.)) per edge (overwrite p with w in LDS), reduce sw/sp.
// phase2: acc += w * xh[src] straight from LDS — no global re-gather of edge data.
__global__ __launch_bounds__(256) void k6_agg(const int* __restrict__ rowptr,
                                              const int* __restrict__ perm,
                                              const int* __restrict__ ei,
                                              const float* __restrict__ p_e,
                                              const float* __restrict__ xh,
                                              const float* __restrict__ a_src,
                                              const float* __restrict__ a_dst,
                                              const float* __restrict__ bias,
                                              float* __restrict__ out) {
    __shared__ __align__(16) float s_w[4][MAXE][4];
    __shared__ int s_src[4][MAXE];
    int wid  = threadIdx.x >> 6;
    int lane = threadIdx.x & 63;
    int n = blockIdx.x * 4 + wid;          // N_NODES % 4 == 0: all waves valid, barriers safe
    int start = rowptr[n], end = rowptr[n + 1];
    int degn = end - start;
    int m = min(degn, MAXE);

    // phase 0: stage edges into LDS (scattered reads happen exactly once)
    for (int i = lane; i < m; i += 64) {
        int e = perm[start + i];
        s_src[wid][i] = ei[e];
        *(float4*)&s_w[wid][i][0] = *(const float4*)(p_e + (size_t)e * 4);
    }
    __syncthreads();

    // phase 1: per-head exp-weight sum + raw-p sum.  lane = slot*4 + h
    int h = lane & 3;
    float adh = a_dst[n * 4 + h];
    float sw = 0.f, sp = 0.f;
    for (int i = lane >> 2; i < m; i += 16) {
        int s   = s_src[wid][i];
        float p = s_w[wid][i][h];
        float w = __expf(lrelu(a_src[(size_t)s * 4 + h] + adh + p));
        s_w[wid][i][h] = w;                // overwrite p with w for phase 2
        sw += w;
        sp += p;
    }
    for (int i = MAXE + (lane >> 2); i < degn; i += 16) {   // overflow (deg>64): ~never
        int e = perm[start + i];
        int s = ei[e];
        float p = p_e[(size_t)e * 4 + h];
        sw += __expf(lrelu(a_src[(size_t)s * 4 + h] + adh + p));
        sp += p;
    }
    sw += __shfl_xor(sw, 4);  sp += __shfl_xor(sp, 4);
    sw += __shfl_xor(sw, 8);  sp += __shfl_xor(sp, 8);
    sw += __shfl_xor(sw, 16); sp += __shfl_xor(sp, 16);
    sw += __shfl_xor(sw, 32); sp += __shfl_xor(sp, 32);

    float al    = sp / fmaxf((float)degn, 1.f);
    float wself = __expf(lrelu(a_src[n * 4 + h] + adh + al));
    float denom = sw + wself + 1e-16f;
    __syncthreads();                        // s_w writes visible before phase 2

    // phase 2: accumulate. lane = h2*16 + c
    int h2 = lane >> 4;
    float d2   = __shfl(denom, h2);
    float ws2  = __shfl(wself, h2);
    float adh2 = __shfl(adh, h2);
    float acc = ws2 * xh[(size_t)n * HC + lane];

    int i = 0;
    for (; i + 4 <= m; i += 4) {
        int s0 = s_src[wid][i], s1 = s_src[wid][i + 1];
        int s2 = s_src[wid][i + 2], s3 = s_src[wid][i + 3];
        float w0 = s_w[wid][i][h2],     w1 = s_w[wid][i + 1][h2];
        float w2 = s_w[wid][i + 2][h2], w3 = s_w[wid][i + 3][h2];
        float x0 = xh[(size_t)s0 * HC + lane];
        float x1 = xh[(size_t)s1 * HC + lane];
        float x2 = xh[(size_t)s2 * HC + lane];
        float x3 = xh[(size_t)s3 * HC + lane];
        acc = fmaf(w0, x0, acc);
        acc = fmaf(w1, x1, acc);
        acc = fmaf(w2, x2, acc);
        acc = fmaf(w3, x3, acc);
    }
    for (; i < m; ++i) {
        int s = s_src[wid][i];
        acc = fmaf(s_w[wid][i][h2], xh[(size_t)s * HC + lane], acc);
    }
    for (int j = MAXE; j < degn; ++j) {     // overflow: recompute from global
        int e = perm[start + j];
        int s = ei[e];
        float p = p_e[(size_t)e * 4 + h2];
        float w = __expf(lrelu(a_src[(size_t)s * 4 + h2] + adh2 + p));
        acc = fmaf(w, xh[(size_t)s * HC + lane], acc);
    }
    out[(size_t)n * HC + lane] = acc / d2 + bias[lane];
}

// ---------------- launcher ----------------
extern "C" void kernel_launch(void* const* d_in, const int* in_sizes, int n_in,
                              void* d_out, int out_size, void* d_ws, size_t ws_size,
                              hipStream_t stream) {
    const float* x         = (const float*)d_in[0];
    const int*   ei        = (const int*)d_in[1];
    const float* edge_attr = (const float*)d_in[2];
    const float* W         = (const float*)d_in[3];
    const float* W_edge    = (const float*)d_in[4];
    const float* att_src   = (const float*)d_in[5];
    const float* att_dst   = (const float*)d_in[6];
    const float* att_edge  = (const float*)d_in[7];
    const float* bias      = (const float*)d_in[8];
    float* out = (float*)d_out;

    char* ws = (char*)d_ws;
    size_t off = 0;
    float* v_edge    = (float*)(ws + off); off += 1024;                      // 256 f
    float* xh        = (float*)(ws + off); off += (size_t)N_NODES * HC * 4;  // 12.8 MB
    float* a_src     = (float*)(ws + off); off += (size_t)N_NODES * 4 * 4;
    float* a_dst     = (float*)(ws + off); off += (size_t)N_NODES * 4 * 4;
    int*   deg       = (int*)(ws + off);   off += (size_t)N_NODES * 4;
    int*   tmp       = (int*)(ws + off);   off += (size_t)N_NODES * 4;
    int*   bsums     = (int*)(ws + off);   off += 1024;
    int*   rowptr    = (int*)(ws + off);   off += (size_t)(N_NODES + 4) * 4;
    int*   cursor    = (int*)(ws + off);   off += (size_t)N_NODES * 4;
    int*   perm      = (int*)(ws + off);   off += (size_t)NE * 4;            // 3.2 MB
    float* p_e       = (float*)(ws + off); off += (size_t)NE * 4 * 4;        // 12.8 MB

    hipMemsetAsync(deg, 0, (size_t)N_NODES * 4, stream);

    k1_vedge<<<1, 256, 0, stream>>>(W_edge, att_edge, v_edge);
    k2_xh<<<(N_NODES + 127) / 128, 256, 0, stream>>>(x, W, att_src, att_dst, xh, a_src, a_dst);
    kp_edge<<<1024, 256, 0, stream>>>(edge_attr, ei, v_edge, p_e, deg);
    int nb = (N_NODES + 255) / 256;   // 196
    k4a_scan<<<nb, 256, 0, stream>>>(deg, tmp, bsums);
    k4b_scan<<<1, 256, 0, stream>>>(bsums, nb);
    k4c_finish<<<nb, 256, 0, stream>>>(tmp, bsums, deg, rowptr, cursor);
    k5_perm<<<(NE + 255) / 256, 256, 0, stream>>>(ei, cursor, perm);
    k6_agg<<<N_NODES / 4, 256, 0, stream>>>(rowptr, perm, ei, p_e, xh,
                                            a_src, a_dst, bias, out);
}

// Round 5
// 466.108 us; speedup vs baseline: 1.0572x; 1.0131x over previous
//
#include <hip/hip_runtime.h>
#include <math.h>

#define N_NODES 50000
#define DIM     128
#define NHEAD   4
#define NCH     16
#define HC      64
#define NE      800000
#define EDIM    64
#define NEG     0.2f
#define MAXE    64

__device__ __forceinline__ float lrelu(float v) { return v > 0.f ? v : NEG * v; }

// ---------------- K1: v_edge[h][d] = sum_c att_edge[h,c] * W_edge[h*16+c, d] ----------------
__global__ void k1_vedge(const float* __restrict__ W_edge, const float* __restrict__ att_edge,
                         float* __restrict__ v_edge) {
    int t = threadIdx.x;          // 256 threads
    int h = t >> 6, d = t & 63;
    float acc = 0.f;
    #pragma unroll
    for (int c = 0; c < NCH; ++c)
        acc = fmaf(att_edge[h * NCH + c], W_edge[(h * NCH + c) * EDIM + d], acc);
    v_edge[h * 64 + d] = acc;
}

// ---------------- K2: xh = x @ W^T  [N,64]; a_src/a_dst [N,4] ----------------
__global__ __launch_bounds__(256) void k2_xh(const float* __restrict__ x, const float* __restrict__ W,
                                             const float* __restrict__ att_src, const float* __restrict__ att_dst,
                                             float* __restrict__ xh, float* __restrict__ a_src,
                                             float* __restrict__ a_dst) {
    __shared__ float Wt[128 * 68];   // Wt[k*68 + col]
    int t = threadIdx.x;
    for (int idx = t; idx < 64 * 128; idx += 256) {
        int col = idx >> 7, k = idx & 127;
        Wt[k * 68 + col] = W[idx];
    }
    __syncthreads();

    int h  = t & 3;
    int rp = t >> 2;                       // 0..63
    int row0 = blockIdx.x * 128 + rp * 2;  // this thread: rows row0, row0+1, head h
    int r0 = min(row0, N_NODES - 1);
    int r1 = min(row0 + 1, N_NODES - 1);
    const float4* x0 = (const float4*)(x + (size_t)r0 * DIM);
    const float4* x1 = (const float4*)(x + (size_t)r1 * DIM);

    float acc0[16], acc1[16];
    #pragma unroll
    for (int c = 0; c < 16; ++c) { acc0[c] = 0.f; acc1[c] = 0.f; }

    for (int k4 = 0; k4 < 32; ++k4) {
        float4 xa = x0[k4];
        float4 xb = x1[k4];
        #pragma unroll
        for (int kk = 0; kk < 4; ++kk) {
            float va = (&xa.x)[kk];
            float vb = (&xb.x)[kk];
            const float* wr = &Wt[(k4 * 4 + kk) * 68 + h * 16];
            #pragma unroll
            for (int j = 0; j < 4; ++j) {
                float4 w = *(const float4*)(wr + 4 * j);
                acc0[4 * j + 0] = fmaf(va, w.x, acc0[4 * j + 0]);
                acc0[4 * j + 1] = fmaf(va, w.y, acc0[4 * j + 1]);
                acc0[4 * j + 2] = fmaf(va, w.z, acc0[4 * j + 2]);
                acc0[4 * j + 3] = fmaf(va, w.w, acc0[4 * j + 3]);
                acc1[4 * j + 0] = fmaf(vb, w.x, acc1[4 * j + 0]);
                acc1[4 * j + 1] = fmaf(vb, w.y, acc1[4 * j + 1]);
                acc1[4 * j + 2] = fmaf(vb, w.z, acc1[4 * j + 2]);
                acc1[4 * j + 3] = fmaf(vb, w.w, acc1[4 * j + 3]);
            }
        }
    }

    if (row0 < N_NODES) {
        float4* o = (float4*)(xh + (size_t)row0 * HC + h * 16);
        o[0] = make_float4(acc0[0], acc0[1], acc0[2], acc0[3]);
        o[1] = make_float4(acc0[4], acc0[5], acc0[6], acc0[7]);
        o[2] = make_float4(acc0[8], acc0[9], acc0[10], acc0[11]);
        o[3] = make_float4(acc0[12], acc0[13], acc0[14], acc0[15]);
        float ss = 0.f, sd = 0.f;
        #pragma unroll
        for (int c = 0; c < 16; ++c) {
            ss = fmaf(acc0[c], att_src[h * 16 + c], ss);
            sd = fmaf(acc0[c], att_dst[h * 16 + c], sd);
        }
        a_src[row0 * 4 + h] = ss;
        a_dst[row0 * 4 + h] = sd;
    }
    if (row0 + 1 < N_NODES) {
        float4* o = (float4*)(xh + (size_t)(row0 + 1) * HC + h * 16);
        o[0] = make_float4(acc1[0], acc1[1], acc1[2], acc1[3]);
        o[1] = make_float4(acc1[4], acc1[5], acc1[6], acc1[7]);
        o[2] = make_float4(acc1[8], acc1[9], acc1[10], acc1[11]);
        o[3] = make_float4(acc1[12], acc1[13], acc1[14], acc1[15]);
        float ss = 0.f, sd = 0.f;
        #pragma unroll
        for (int c = 0; c < 16; ++c) {
            ss = fmaf(acc1[c], att_src[h * 16 + c], ss);
            sd = fmaf(acc1[c], att_dst[h * 16 + c], sd);
        }
        a_src[(row0 + 1) * 4 + h] = ss;
        a_dst[(row0 + 1) * 4 + h] = sd;
    }
}

// ---------------- KA: deg histogram (int atomics only, coalesced dst read) ----------------
__global__ __launch_bounds__(256) void ka_deg(const int* __restrict__ ei, int* __restrict__ deg) {
    int e = blockIdx.x * 256 + threadIdx.x;
    if (e >= NE) return;
    atomicAdd(deg + ei[NE + e], 1);
}

// ---------------- K4: 3-kernel exclusive scan of deg -> rowptr, cursor ----------------
__global__ void k4a_scan(const int* __restrict__ deg, int* __restrict__ tmp, int* __restrict__ bsums) {
    int t = threadIdx.x;
    int i = blockIdx.x * 256 + t;
    int v = (i < N_NODES) ? deg[i] : 0;
    int lane = t & 63, w = t >> 6;
    int xv = v;
    #pragma unroll
    for (int o = 1; o < 64; o <<= 1) {
        int y = __shfl_up(xv, o);
        if (lane >= o) xv += y;
    }
    __shared__ int wtot[4];
    if (lane == 63) wtot[w] = xv;
    __syncthreads();
    int add = 0;
    #pragma unroll
    for (int j = 0; j < 4; ++j)
        if (j < w) add += wtot[j];
    xv += add;
    if (i < N_NODES) tmp[i] = xv;            // inclusive within block
    if (t == 255) bsums[blockIdx.x] = xv;    // block total
}

__global__ void k4b_scan(int* __restrict__ bsums, int nb) {
    int t = threadIdx.x;
    int v = (t < nb) ? bsums[t] : 0;
    int lane = t & 63, w = t >> 6;
    int xv = v;
    #pragma unroll
    for (int o = 1; o < 64; o <<= 1) {
        int y = __shfl_up(xv, o);
        if (lane >= o) xv += y;
    }
    __shared__ int wtot[4];
    if (lane == 63) wtot[w] = xv;
    __syncthreads();
    int add = 0;
    #pragma unroll
    for (int j = 0; j < 4; ++j)
        if (j < w) add += wtot[j];
    xv += add;
    if (t < nb) bsums[t] = xv - v;           // exclusive block offset
}

__global__ void k4c_finish(const int* __restrict__ tmp, const int* __restrict__ bsums,
                           const int* __restrict__ deg, int* __restrict__ rowptr,
                           int* __restrict__ cursor) {
    int i = blockIdx.x * 256 + threadIdx.x;
    if (i >= N_NODES) return;
    int incl = tmp[i] + bsums[i >> 8];
    rowptr[i + 1] = incl;
    cursor[i] = incl - deg[i];
    if (i == 0) rowptr[0] = 0;
}

// ---------------- KP: wave-cooperative edge pass, CSR-direct scatter ----------------
// 16 lanes per edge, 4 edges per wave iteration: one fully-coalesced 1KB edge_attr load.
// Scatters {src, p[4]} directly to the CSR slot (pos via cursor atomic) — no k5, and k6
// reads everything contiguously.
__global__ __launch_bounds__(256) void kp_csr(const float* __restrict__ edge_attr,
                                              const int* __restrict__ ei,
                                              const float* __restrict__ v_edge,
                                              int* __restrict__ cursor,
                                              int* __restrict__ csr_src,
                                              float* __restrict__ csr_p) {
    int lane = threadIdx.x & 63;
    int q = lane & 15;          // feature quarter 0..15 (features q*4..q*4+3)
    float4 w0 = *(const float4*)(v_edge + 0 * 64 + q * 4);
    float4 w1 = *(const float4*)(v_edge + 1 * 64 + q * 4);
    float4 w2 = *(const float4*)(v_edge + 2 * 64 + q * 4);
    float4 w3 = *(const float4*)(v_edge + 3 * 64 + q * 4);

    int wave   = (blockIdx.x * 256 + threadIdx.x) >> 6;
    int nwaves = gridDim.x * 4;
    for (int g = wave; g < NE / 4; g += nwaves) {
        float4 v = *(const float4*)(edge_attr + (size_t)g * 256 + lane * 4);
        float p0 = fmaf(v.x, w0.x, fmaf(v.y, w0.y, fmaf(v.z, w0.z, v.w * w0.w)));
        float p1 = fmaf(v.x, w1.x, fmaf(v.y, w1.y, fmaf(v.z, w1.z, v.w * w1.w)));
        float p2 = fmaf(v.x, w2.x, fmaf(v.y, w2.y, fmaf(v.z, w2.z, v.w * w2.w)));
        float p3 = fmaf(v.x, w3.x, fmaf(v.y, w3.y, fmaf(v.z, w3.z, v.w * w3.w)));
        #pragma unroll
        for (int m = 1; m < 16; m <<= 1) {
            p0 += __shfl_xor(p0, m);
            p1 += __shfl_xor(p1, m);
            p2 += __shfl_xor(p2, m);
            p3 += __shfl_xor(p3, m);
        }
        if (q == 0) {
            int e = g * 4 + (lane >> 4);
            int src = ei[e];
            int dst = ei[NE + e];
            int pos = atomicAdd(cursor + dst, 1);
            csr_src[pos] = src;
            *(float4*)(csr_p + (size_t)pos * 4) = make_float4(p0, p1, p2, p3);
        }
    }
}

// ---------------- K6: wave per node, contiguous CSR + LDS staging ----------------
__global__ __launch_bounds__(256) void k6_agg(const int* __restrict__ rowptr,
                                              const int* __restrict__ csr_src,
                                              const float* __restrict__ csr_p,
                                              const float* __restrict__ xh,
                                              const float* __restrict__ a_src,
                                              const float* __restrict__ a_dst,
                                              const float* __restrict__ bias,
                                              float* __restrict__ out) {
    __shared__ __align__(16) float s_w[4][MAXE][4];
    __shared__ int s_src[4][MAXE];
    int wid  = threadIdx.x >> 6;
    int lane = threadIdx.x & 63;
    int n = blockIdx.x * 4 + wid;          // N_NODES % 4 == 0: all waves valid, barriers safe
    int start = rowptr[n], end = rowptr[n + 1];
    int degn = end - start;
    int m = min(degn, MAXE);

    // phase 0: stage this node's CSR slice into LDS — fully contiguous loads
    for (int i = lane; i < m; i += 64) {
        s_src[wid][i] = csr_src[start + i];
        *(float4*)&s_w[wid][i][0] = *(const float4*)(csr_p + (size_t)(start + i) * 4);
    }
    __syncthreads();

    // phase 1: per-head exp-weight sum + raw-p sum.  lane = slot*4 + h
    int h = lane & 3;
    float adh = a_dst[n * 4 + h];
    float sw = 0.f, sp = 0.f;
    for (int i = lane >> 2; i < m; i += 16) {
        int s   = s_src[wid][i];
        float p = s_w[wid][i][h];
        float w = __expf(lrelu(a_src[(size_t)s * 4 + h] + adh + p));
        s_w[wid][i][h] = w;                // overwrite p with w for phase 2
        sw += w;
        sp += p;
    }
    for (int i = MAXE + (lane >> 2); i < degn; i += 16) {   // overflow (deg>64): ~never
        int s = csr_src[start + i];
        float p = csr_p[(size_t)(start + i) * 4 + h];
        sw += __expf(lrelu(a_src[(size_t)s * 4 + h] + adh + p));
        sp += p;
    }
    sw += __shfl_xor(sw, 4);  sp += __shfl_xor(sp, 4);
    sw += __shfl_xor(sw, 8);  sp += __shfl_xor(sp, 8);
    sw += __shfl_xor(sw, 16); sp += __shfl_xor(sp, 16);
    sw += __shfl_xor(sw, 32); sp += __shfl_xor(sp, 32);

    float al    = sp / fmaxf((float)degn, 1.f);
    float wself = __expf(lrelu(a_src[n * 4 + h] + adh + al));
    float denom = sw + wself + 1e-16f;
    __syncthreads();                        // s_w writes visible before phase 2

    // phase 2: accumulate. lane = h2*16 + c
    int h2 = lane >> 4;
    float d2   = __shfl(denom, h2);
    float ws2  = __shfl(wself, h2);
    float adh2 = __shfl(adh, h2);
    float acc = ws2 * xh[(size_t)n * HC + lane];

    int i = 0;
    for (; i + 4 <= m; i += 4) {
        int s0 = s_src[wid][i], s1 = s_src[wid][i + 1];
        int s2 = s_src[wid][i + 2], s3 = s_src[wid][i + 3];
        float w0 = s_w[wid][i][h2],     w1 = s_w[wid][i + 1][h2];
        float w2 = s_w[wid][i + 2][h2], w3 = s_w[wid][i + 3][h2];
        float x0 = xh[(size_t)s0 * HC + lane];
        float x1 = xh[(size_t)s1 * HC + lane];
        float x2 = xh[(size_t)s2 * HC + lane];
        float x3 = xh[(size_t)s3 * HC + lane];
        acc = fmaf(w0, x0, acc);
        acc = fmaf(w1, x1, acc);
        acc = fmaf(w2, x2, acc);
        acc = fmaf(w3, x3, acc);
    }
    for (; i < m; ++i) {
        int s = s_src[wid][i];
        acc = fmaf(s_w[wid][i][h2], xh[(size_t)s * HC + lane], acc);
    }
    for (int j = MAXE; j < degn; ++j) {     // overflow: recompute from contiguous CSR
        int s = csr_src[start + j];
        float p = csr_p[(size_t)(start + j) * 4 + h2];
        float w = __expf(lrelu(a_src[(size_t)s * 4 + h2] + adh2 + p));
        acc = fmaf(w, xh[(size_t)s * HC + lane], acc);
    }
    out[(size_t)n * HC + lane] = acc / d2 + bias[lane];
}

// ---------------- launcher ----------------
extern "C" void kernel_launch(void* const* d_in, const int* in_sizes, int n_in,
                              void* d_out, int out_size, void* d_ws, size_t ws_size,
                              hipStream_t stream) {
    const float* x         = (const float*)d_in[0];
    const int*   ei        = (const int*)d_in[1];
    const float* edge_attr = (const float*)d_in[2];
    const float* W         = (const float*)d_in[3];
    const float* W_edge    = (const float*)d_in[4];
    const float* att_src   = (const float*)d_in[5];
    const float* att_dst   = (const float*)d_in[6];
    const float* att_edge  = (const float*)d_in[7];
    const float* bias      = (const float*)d_in[8];
    float* out = (float*)d_out;

    char* ws = (char*)d_ws;
    size_t off = 0;
    float* v_edge    = (float*)(ws + off); off += 1024;                      // 256 f
    float* xh        = (float*)(ws + off); off += (size_t)N_NODES * HC * 4;  // 12.8 MB
    float* a_src     = (float*)(ws + off); off += (size_t)N_NODES * 4 * 4;
    float* a_dst     = (float*)(ws + off); off += (size_t)N_NODES * 4 * 4;
    int*   deg       = (int*)(ws + off);   off += (size_t)N_NODES * 4;
    int*   tmp       = (int*)(ws + off);   off += (size_t)N_NODES * 4;
    int*   bsums     = (int*)(ws + off);   off += 1024;
    int*   rowptr    = (int*)(ws + off);   off += (size_t)(N_NODES + 4) * 4;
    int*   cursor    = (int*)(ws + off);   off += (size_t)N_NODES * 4;
    int*   csr_src   = (int*)(ws + off);   off += (size_t)NE * 4;            // 3.2 MB
    float* csr_p     = (float*)(ws + off); off += (size_t)NE * 4 * 4;        // 12.8 MB

    hipMemsetAsync(deg, 0, (size_t)N_NODES * 4, stream);

    k1_vedge<<<1, 256, 0, stream>>>(W_edge, att_edge, v_edge);
    k2_xh<<<(N_NODES + 127) / 128, 256, 0, stream>>>(x, W, att_src, att_dst, xh, a_src, a_dst);
    ka_deg<<<(NE + 255) / 256, 256, 0, stream>>>(ei, deg);
    int nb = (N_NODES + 255) / 256;   // 196
    k4a_scan<<<nb, 256, 0, stream>>>(deg, tmp, bsums);
    k4b_scan<<<1, 256, 0, stream>>>(bsums, nb);
    k4c_finish<<<nb, 256, 0, stream>>>(tmp, bsums, deg, rowptr, cursor);
    kp_csr<<<1024, 256, 0, stream>>>(edge_attr, ei, v_edge, cursor, csr_src, csr_p);
    k6_agg<<<N_NODES / 4, 256, 0, stream>>>(rowptr, csr_src, csr_p, xh,
                                            a_src, a_dst, bias, out);
}